// Round 4
// baseline (235.221 us; speedup 1.0000x reference)
//
#include <hip/hip_runtime.h>

// Fused SNN forward for MI355X (gfx950) — round 3 (compile fix).
// One block (512 threads = 8 waves) per image; 3 pool units per thread.
// Output-split: lanes 0-31 of each wave accumulate FC outputs 0-4, lanes
// 32-63 outputs 5-9. Spike counts cross the half-wave via ONE packed-int
// shfl_xor(32) per timestep. Per-t reduce: xor16 -> fold(5->3) -> xor8 ->
// 8 rows/wave stored to stride-165 LDS (conflict-free). Zero barriers in
// the 16-step loop; one final 64-row reduce + 10-lane LIF-2 scan.

__global__ __launch_bounds__(512, 6) void snn_fused_kernel(
    const float* __restrict__ x,       // [4096, 1, 28, 28]
    const float* __restrict__ conv_w,  // [8, 1, 3, 3]
    const float* __restrict__ fc_w,    // [10, 1352]
    float* __restrict__ out)           // [4096, 10]
{
    const int b    = blockIdx.x;
    const int tid  = threadIdx.x;
    const int lane = tid & 63;
    const int wid  = tid >> 6;

    __shared__ float sx[784];            // 28x28 image
    __shared__ float scw[72];            // conv weights
    __shared__ float sred[64 * 165];     // 64 rows x (16t*10o), stride 165
    __shared__ float scur2[160];         // [t][o]

    {
        const float4* xg  = reinterpret_cast<const float4*>(x + (size_t)b * 784);
        float4*       sx4 = reinterpret_cast<float4*>(sx);
        if (tid < 196) sx4[tid] = xg[tid];
        if (tid < 72)  scw[tid] = conv_w[tid];
    }
    __syncthreads();

    const bool hi32 = (lane & 32) != 0;

    // ---- per-thread state ----
    float cur[3][4];   // conv out, own units (const over t)
    float mem[3][4];   // LIF-1 membranes, own units
    float wl[6][5];    // 0.25*fc_w[o][u] : j<3 own units, j>=3 partner units;
                       // k=0..4 -> output o = hi32 ? k+5 : k

    #pragma unroll
    for (int i = 0; i < 3; ++i) {
        const int u      = tid + 512 * i;
        const bool valid = (u < 1352);
        const int uu  = valid ? u : 0;
        const int k   = uu / 169;
        const int rem = uu - k * 169;
        const int pr  = rem / 13;
        const int pc  = rem - pr * 13;

        float cw[9];
        #pragma unroll
        for (int q = 0; q < 9; ++q) cw[q] = scw[k * 9 + q];

        float xr[4][4];
        #pragma unroll
        for (int r = 0; r < 4; ++r) {
            const float2* row = reinterpret_cast<const float2*>(&sx[(2 * pr + r) * 28 + 2 * pc]);
            const float2 a = row[0], c2 = row[1];
            xr[r][0] = a.x; xr[r][1] = a.y; xr[r][2] = c2.x; xr[r][3] = c2.y;
        }

        #pragma unroll
        for (int dr = 0; dr < 2; ++dr)
            #pragma unroll
            for (int dc = 0; dc < 2; ++dc) {
                float acc = 0.0f;
                #pragma unroll
                for (int ki = 0; ki < 3; ++ki)
                    #pragma unroll
                    for (int kj = 0; kj < 3; ++kj)
                        acc += xr[dr + ki][dc + kj] * cw[ki * 3 + kj];
                cur[i][dr * 2 + dc] = valid ? acc : 0.0f;
                mem[i][dr * 2 + dc] = 0.0f;
            }
    }

    // weights: own units (j=0..2) and lane^32-partner units (j=3..5)
    #pragma unroll
    for (int j = 0; j < 6; ++j) {
        const int bt     = (j < 3) ? tid : (tid ^ 32);
        const int u      = bt + 512 * (j % 3);
        const bool valid = (u < 1352);
        const int uu     = valid ? u : 0;
        #pragma unroll
        for (int k = 0; k < 5; ++k) {
            const int o = hi32 ? (k + 5) : k;
            wl[j][k] = valid ? 0.25f * fc_w[o * 1352 + uu] : 0.0f;
        }
    }

    // stageA: one LIF step on own units + packed count exchange + 30 FMA
    auto stageA = [&](float nv[5]) {
        int c[3];
        #pragma unroll
        for (int i = 0; i < 3; ++i) {
            int ci = 0;
            #pragma unroll
            for (int j2 = 0; j2 < 4; ++j2) {
                float m  = __builtin_fmaf(0.5f, mem[i][j2], cur[i][j2]);
                float ms = m - 1.0f;                  // spike iff ms > 0
                bool  sp = ms > 0.0f;
                mem[i][j2] = sp ? ms : m;
                ci += sp ? 1 : 0;
            }
            c[i] = ci;
        }
        const int pk  = c[0] | (c[1] << 4) | (c[2] << 8);
        const int ppk = __shfl_xor(pk, 32);           // partner's counts
        #pragma unroll
        for (int k = 0; k < 5; ++k) nv[k] = 0.0f;
        #pragma unroll
        for (int i = 0; i < 3; ++i) {                 // own-unit FMAs (hide shfl)
            const float f = (float)c[i];
            #pragma unroll
            for (int k = 0; k < 5; ++k) nv[k] = __builtin_fmaf(wl[i][k], f, nv[k]);
        }
        #pragma unroll
        for (int i = 0; i < 3; ++i) {                 // partner-unit FMAs
            const float f = (float)((ppk >> (4 * i)) & 15);
            #pragma unroll
            for (int k = 0; k < 5; ++k) nv[k] = __builtin_fmaf(wl[3 + i][k], f, nv[k]);
        }
    };

    float v[5];
    stageA(v);                                        // t = 0 partials

    const bool hi16 = (lane & 16) != 0;
    const int  row  = wid * 8 + (lane & 7);
    const int  q    = lane >> 4;                      // quadrant 0..3
    const int  bo   = (q & 1) * 2 + (q >> 1) * 5;     // {0,2,5,7}
    const int  to   = 4 + (q >> 1) * 5;               // {4,4,9,9}

    #pragma unroll
    for (int t = 0; t < 16; ++t) {
        // level-2 reduce issue (xor16) — latency hidden by next stageA
        float s2[5];
        #pragma unroll
        for (int k = 0; k < 5; ++k) s2[k] = __shfl_xor(v[k], 16);

        float nv[5];
        if (t < 15) {
            stageA(nv);
        } else {
            #pragma unroll
            for (int k = 0; k < 5; ++k) nv[k] = 0.0f;
        }

        // fold 5 -> 3 and level-3 (xor8)
        const float a0 = v[0] + s2[0], a1 = v[1] + s2[1], a2 = v[2] + s2[2],
                    a3 = v[3] + s2[3], a4 = v[4] + s2[4];
        float w0 = hi16 ? a2 : a0;
        float w1 = hi16 ? a3 : a1;
        float w2 = a4;
        w0 += __shfl_xor(w0, 8);
        w1 += __shfl_xor(w1, 8);
        w2 += __shfl_xor(w2, 8);

        // 8 rows per wave; duplicate same-value writes of w2 are benign
        if ((lane & 8) == 0) {
            const int base = row * 165 + t * 10;
            sred[base + bo]     = w0;
            sred[base + bo + 1] = w1;
            sred[base + to]     = w2;
        }

        #pragma unroll
        for (int k = 0; k < 5; ++k) v[k] = nv[k];
    }
    __syncthreads();

    // ---- final reduce: 160 threads, one (t,o) each, 64 rows ----
    if (tid < 160) {
        const int t = tid / 10;
        const int o = tid - t * 10;
        float sum = 0.0f;
        #pragma unroll
        for (int r = 0; r < 64; ++r)
            sum += sred[r * 165 + t * 10 + o];
        scur2[tid] = sum;
    }
    __syncthreads();

    // ---- LIF-2 scan, 10 lanes ----
    if (tid < 10) {
        float m2 = 0.0f, cnt = 0.0f;
        #pragma unroll
        for (int t = 0; t < 16; ++t) {
            m2 = __builtin_fmaf(0.5f, m2, scur2[t * 10 + tid]);
            float ms = m2 - 1.0f;
            bool  sp = ms > 0.0f;
            m2  = sp ? ms : m2;
            cnt += sp ? 1.0f : 0.0f;
        }
        out[(size_t)b * 10 + tid] = cnt;
    }
}

extern "C" void kernel_launch(void* const* d_in, const int* in_sizes, int n_in,
                              void* d_out, int out_size, void* d_ws, size_t ws_size,
                              hipStream_t stream) {
    const float* x      = (const float*)d_in[0];  // 4096*784
    const float* conv_w = (const float*)d_in[1];  // 72
    const float* fc_w   = (const float*)d_in[2];  // 13520
    float* out          = (float*)d_out;          // 40960

    const int B = in_sizes[0] / 784;              // 4096
    snn_fused_kernel<<<B, 512, 0, stream>>>(x, conv_w, fc_w, out);
}

// Round 5
// 117.344 us; speedup vs baseline: 2.0045x; 2.0045x over previous
//
#include <hip/hip_runtime.h>

// Fused SNN forward for MI355X (gfx950) — round 5.
// Identical to round 3 except __launch_bounds__(512, 4): the (512,6) variant
// capped the allocator at ~85 VGPRs and spilled the 54-float per-thread state
// to scratch (FETCH 224 MB, WRITE 466 MB, VGPR_Count=40). With min-waves=4
// the budget is 128 VGPRs; state stays register-resident. LDS 46.6 KB ->
// 2 blocks/CU (16 waves, 50% occupancy), VGPR-bounded.
//
// One block (512 threads = 8 waves) per image; 3 pool units per thread.
// Output-split: lanes 0-31 accumulate FC outputs 0-4, lanes 32-63 outputs
// 5-9; spike counts cross via ONE packed-int shfl_xor(32). Per-t reduce:
// xor16 -> fold(5->3) -> xor8 -> 8 rows/wave to stride-165 LDS. Zero
// barriers in the 16-step loop; final 64-row reduce + 10-lane LIF-2 scan.

__global__ __launch_bounds__(512, 4) void snn_fused_kernel(
    const float* __restrict__ x,       // [4096, 1, 28, 28]
    const float* __restrict__ conv_w,  // [8, 1, 3, 3]
    const float* __restrict__ fc_w,    // [10, 1352]
    float* __restrict__ out)           // [4096, 10]
{
    const int b    = blockIdx.x;
    const int tid  = threadIdx.x;
    const int lane = tid & 63;
    const int wid  = tid >> 6;

    __shared__ float sx[784];            // 28x28 image
    __shared__ float scw[72];            // conv weights
    __shared__ float sred[64 * 165];     // 64 rows x (16t*10o), stride 165
    __shared__ float scur2[160];         // [t][o]

    {
        const float4* xg  = reinterpret_cast<const float4*>(x + (size_t)b * 784);
        float4*       sx4 = reinterpret_cast<float4*>(sx);
        if (tid < 196) sx4[tid] = xg[tid];
        if (tid < 72)  scw[tid] = conv_w[tid];
    }
    __syncthreads();

    const bool hi32 = (lane & 32) != 0;

    // ---- per-thread state ----
    float cur[3][4];   // conv out, own units (const over t)
    float mem[3][4];   // LIF-1 membranes, own units
    float wl[6][5];    // 0.25*fc_w[o][u] : j<3 own units, j>=3 partner units;
                       // k=0..4 -> output o = hi32 ? k+5 : k

    #pragma unroll
    for (int i = 0; i < 3; ++i) {
        const int u      = tid + 512 * i;
        const bool valid = (u < 1352);
        const int uu  = valid ? u : 0;
        const int k   = uu / 169;
        const int rem = uu - k * 169;
        const int pr  = rem / 13;
        const int pc  = rem - pr * 13;

        float cw[9];
        #pragma unroll
        for (int q = 0; q < 9; ++q) cw[q] = scw[k * 9 + q];

        float xr[4][4];
        #pragma unroll
        for (int r = 0; r < 4; ++r) {
            const float2* row = reinterpret_cast<const float2*>(&sx[(2 * pr + r) * 28 + 2 * pc]);
            const float2 a = row[0], c2 = row[1];
            xr[r][0] = a.x; xr[r][1] = a.y; xr[r][2] = c2.x; xr[r][3] = c2.y;
        }

        #pragma unroll
        for (int dr = 0; dr < 2; ++dr)
            #pragma unroll
            for (int dc = 0; dc < 2; ++dc) {
                float acc = 0.0f;
                #pragma unroll
                for (int ki = 0; ki < 3; ++ki)
                    #pragma unroll
                    for (int kj = 0; kj < 3; ++kj)
                        acc += xr[dr + ki][dc + kj] * cw[ki * 3 + kj];
                cur[i][dr * 2 + dc] = valid ? acc : 0.0f;
                mem[i][dr * 2 + dc] = 0.0f;
            }
    }

    // weights: own units (j=0..2) and lane^32-partner units (j=3..5)
    #pragma unroll
    for (int j = 0; j < 6; ++j) {
        const int bt     = (j < 3) ? tid : (tid ^ 32);
        const int u      = bt + 512 * (j % 3);
        const bool valid = (u < 1352);
        const int uu     = valid ? u : 0;
        #pragma unroll
        for (int k = 0; k < 5; ++k) {
            const int o = hi32 ? (k + 5) : k;
            wl[j][k] = valid ? 0.25f * fc_w[o * 1352 + uu] : 0.0f;
        }
    }

    // stageA: one LIF step on own units + packed count exchange + 30 FMA
    auto stageA = [&](float nv[5]) {
        int c[3];
        #pragma unroll
        for (int i = 0; i < 3; ++i) {
            int ci = 0;
            #pragma unroll
            for (int j2 = 0; j2 < 4; ++j2) {
                float m  = __builtin_fmaf(0.5f, mem[i][j2], cur[i][j2]);
                float ms = m - 1.0f;                  // spike iff ms > 0
                bool  sp = ms > 0.0f;
                mem[i][j2] = sp ? ms : m;
                ci += sp ? 1 : 0;
            }
            c[i] = ci;
        }
        const int pk  = c[0] | (c[1] << 4) | (c[2] << 8);
        const int ppk = __shfl_xor(pk, 32);           // partner's counts
        #pragma unroll
        for (int k = 0; k < 5; ++k) nv[k] = 0.0f;
        #pragma unroll
        for (int i = 0; i < 3; ++i) {                 // own-unit FMAs (hide shfl)
            const float f = (float)c[i];
            #pragma unroll
            for (int k = 0; k < 5; ++k) nv[k] = __builtin_fmaf(wl[i][k], f, nv[k]);
        }
        #pragma unroll
        for (int i = 0; i < 3; ++i) {                 // partner-unit FMAs
            const float f = (float)((ppk >> (4 * i)) & 15);
            #pragma unroll
            for (int k = 0; k < 5; ++k) nv[k] = __builtin_fmaf(wl[3 + i][k], f, nv[k]);
        }
    };

    float v[5];
    stageA(v);                                        // t = 0 partials

    const bool hi16 = (lane & 16) != 0;
    const int  row  = wid * 8 + (lane & 7);
    const int  q    = lane >> 4;                      // quadrant 0..3
    const int  bo   = (q & 1) * 2 + (q >> 1) * 5;     // {0,2,5,7}
    const int  to   = 4 + (q >> 1) * 5;               // {4,4,9,9}

    #pragma unroll
    for (int t = 0; t < 16; ++t) {
        // level-2 reduce issue (xor16) — latency hidden by next stageA
        float s2[5];
        #pragma unroll
        for (int k = 0; k < 5; ++k) s2[k] = __shfl_xor(v[k], 16);

        float nv[5];
        if (t < 15) {
            stageA(nv);
        } else {
            #pragma unroll
            for (int k = 0; k < 5; ++k) nv[k] = 0.0f;
        }

        // fold 5 -> 3 and level-3 (xor8)
        const float a0 = v[0] + s2[0], a1 = v[1] + s2[1], a2 = v[2] + s2[2],
                    a3 = v[3] + s2[3], a4 = v[4] + s2[4];
        float w0 = hi16 ? a2 : a0;
        float w1 = hi16 ? a3 : a1;
        float w2 = a4;
        w0 += __shfl_xor(w0, 8);
        w1 += __shfl_xor(w1, 8);
        w2 += __shfl_xor(w2, 8);

        // 8 rows per wave; duplicate same-value writes of w2 are benign
        if ((lane & 8) == 0) {
            const int base = row * 165 + t * 10;
            sred[base + bo]     = w0;
            sred[base + bo + 1] = w1;
            sred[base + to]     = w2;
        }

        #pragma unroll
        for (int k = 0; k < 5; ++k) v[k] = nv[k];
    }
    __syncthreads();

    // ---- final reduce: 160 threads, one (t,o) each, 64 rows ----
    if (tid < 160) {
        const int t = tid / 10;
        const int o = tid - t * 10;
        float sum = 0.0f;
        #pragma unroll
        for (int r = 0; r < 64; ++r)
            sum += sred[r * 165 + t * 10 + o];
        scur2[tid] = sum;
    }
    __syncthreads();

    // ---- LIF-2 scan, 10 lanes ----
    if (tid < 10) {
        float m2 = 0.0f, cnt = 0.0f;
        #pragma unroll
        for (int t = 0; t < 16; ++t) {
            m2 = __builtin_fmaf(0.5f, m2, scur2[t * 10 + tid]);
            float ms = m2 - 1.0f;
            bool  sp = ms > 0.0f;
            m2  = sp ? ms : m2;
            cnt += sp ? 1.0f : 0.0f;
        }
        out[(size_t)b * 10 + tid] = cnt;
    }
}

extern "C" void kernel_launch(void* const* d_in, const int* in_sizes, int n_in,
                              void* d_out, int out_size, void* d_ws, size_t ws_size,
                              hipStream_t stream) {
    const float* x      = (const float*)d_in[0];  // 4096*784
    const float* conv_w = (const float*)d_in[1];  // 72
    const float* fc_w   = (const float*)d_in[2];  // 13520
    float* out          = (float*)d_out;          // 40960

    const int B = in_sizes[0] / 784;              // 4096
    snn_fused_kernel<<<B, 512, 0, stream>>>(x, conv_w, fc_w, out);
}

// Round 6
// 112.746 us; speedup vs baseline: 2.0863x; 1.0408x over previous
//
#include <hip/hip_runtime.h>

// Fused SNN forward for MI355X (gfx950) — round 6.
// Round-5 structure + (a) packed dual-fp32 math (v_pk_fma_f32 via float2
// ext-vectors) in LIF + FC + reduce, (b) one extra xor4 reduce level so
// sred shrinks 42KB -> 21KB (total LDS ~25KB -> up to 4 blocks/CU).
//
// One block (512 threads = 8 waves) per image; 3 pool units per thread.
// Lanes 0-31 accumulate FC outputs 0-4, lanes 32-63 outputs 5-9; spike
// counts (kept as floats) cross the half-wave via 3 shfl_xor(32). Per-t
// reduce: xor16 -> fold(5->3) -> xor8 -> xor4 -> 4 rows/wave to stride-165
// LDS. Zero barriers in the 16-step loop; final 32-row reduce + 10-lane
// LIF-2 scan.

typedef float v2f __attribute__((ext_vector_type(2)));

#if __has_builtin(__builtin_elementwise_fma)
#define VFMA(a, b, c) __builtin_elementwise_fma((a), (b), (c))
#else
#define VFMA(a, b, c) ((a) * (b) + (c))
#endif

__global__ __launch_bounds__(512, 4) void snn_fused_kernel(
    const float* __restrict__ x,       // [4096, 1, 28, 28]
    const float* __restrict__ conv_w,  // [8, 1, 3, 3]
    const float* __restrict__ fc_w,    // [10, 1352]
    float* __restrict__ out)           // [4096, 10]
{
    const int b    = blockIdx.x;
    const int tid  = threadIdx.x;
    const int lane = tid & 63;
    const int wid  = tid >> 6;

    __shared__ float sx[784];            // 28x28 image
    __shared__ float scw[72];            // conv weights
    __shared__ float sred[32 * 165];     // 32 rows x (16t*10o), stride 165
    __shared__ float scur2[160];         // [t][o]

    {
        const float4* xg  = reinterpret_cast<const float4*>(x + (size_t)b * 784);
        float4*       sx4 = reinterpret_cast<float4*>(sx);
        if (tid < 196) sx4[tid] = xg[tid];
        if (tid < 72)  scw[tid] = conv_w[tid];
    }
    __syncthreads();

    const bool hi32 = (lane & 32) != 0;
    const bool hi16 = (lane & 16) != 0;

    // ---- per-thread state (packed pairs) ----
    v2f cur2[3][2];    // conv out: [unit][{cells01, cells23}]
    v2f mem2[3][2];    // LIF-1 membranes
    v2f wl01[6], wl23[6];  // 0.25*fc_w for outputs {k0,k1},{k2,k3}
    float wl4[6];          // output k4

    #pragma unroll
    for (int i = 0; i < 3; ++i) {
        const int u      = tid + 512 * i;
        const bool valid = (u < 1352);
        const int uu  = valid ? u : 0;
        const int k   = uu / 169;
        const int rem = uu - k * 169;
        const int pr  = rem / 13;
        const int pc  = rem - pr * 13;

        float cw[9];
        #pragma unroll
        for (int q = 0; q < 9; ++q) cw[q] = scw[k * 9 + q];

        float xr[4][4];
        #pragma unroll
        for (int r = 0; r < 4; ++r) {
            const float2* row = reinterpret_cast<const float2*>(&sx[(2 * pr + r) * 28 + 2 * pc]);
            const float2 a = row[0], c2 = row[1];
            xr[r][0] = a.x; xr[r][1] = a.y; xr[r][2] = c2.x; xr[r][3] = c2.y;
        }

        float cell[2][2];
        #pragma unroll
        for (int dr = 0; dr < 2; ++dr)
            #pragma unroll
            for (int dc = 0; dc < 2; ++dc) {
                float acc = 0.0f;
                #pragma unroll
                for (int ki = 0; ki < 3; ++ki)
                    #pragma unroll
                    for (int kj = 0; kj < 3; ++kj)
                        acc += xr[dr + ki][dc + kj] * cw[ki * 3 + kj];
                cell[dr][dc] = valid ? acc : 0.0f;
            }
        cur2[i][0] = (v2f){cell[0][0], cell[0][1]};
        cur2[i][1] = (v2f){cell[1][0], cell[1][1]};
        mem2[i][0] = (v2f){0.0f, 0.0f};
        mem2[i][1] = (v2f){0.0f, 0.0f};
    }

    // weights: own units (j=0..2) and lane^32-partner units (j=3..5)
    #pragma unroll
    for (int j = 0; j < 6; ++j) {
        const int bt     = (j < 3) ? tid : (tid ^ 32);
        const int u      = bt + 512 * (j % 3);
        const bool valid = (u < 1352);
        const int uu     = valid ? u : 0;
        const int ob     = hi32 ? 5 : 0;
        const float sc   = valid ? 0.25f : 0.0f;
        wl01[j] = (v2f){sc * fc_w[(ob + 0) * 1352 + uu], sc * fc_w[(ob + 1) * 1352 + uu]};
        wl23[j] = (v2f){sc * fc_w[(ob + 2) * 1352 + uu], sc * fc_w[(ob + 3) * 1352 + uu]};
        wl4[j]  = sc * fc_w[(ob + 4) * 1352 + uu];
    }

    const v2f half2 = (v2f){0.5f, 0.5f};
    const v2f one2  = (v2f){1.0f, 1.0f};

    // stageA: one LIF step on own units (packed) + float count exchange + FC
    auto stageA = [&](v2f& nv01, v2f& nv23, float& nv4) {
        float c[3];
        #pragma unroll
        for (int i = 0; i < 3; ++i) {
            v2f m01 = VFMA(half2, mem2[i][0], cur2[i][0]);
            v2f m23 = VFMA(half2, mem2[i][1], cur2[i][1]);
            v2f ms01 = m01 - one2;
            v2f ms23 = m23 - one2;
            v2f sp01, sp23;
            sp01.x = ms01.x > 0.0f ? 1.0f : 0.0f;
            sp01.y = ms01.y > 0.0f ? 1.0f : 0.0f;
            sp23.x = ms23.x > 0.0f ? 1.0f : 0.0f;
            sp23.y = ms23.y > 0.0f ? 1.0f : 0.0f;
            mem2[i][0] = m01 - sp01;          // == sp ? m-1 : m (bit-identical)
            mem2[i][1] = m23 - sp23;
            v2f s = sp01 + sp23;
            c[i] = s.x + s.y;                  // 0..4 exact
        }
        float p[3];
        p[0] = __shfl_xor(c[0], 32);
        p[1] = __shfl_xor(c[1], 32);
        p[2] = __shfl_xor(c[2], 32);

        nv01 = (v2f){0.0f, 0.0f};
        nv23 = (v2f){0.0f, 0.0f};
        nv4  = 0.0f;
        #pragma unroll
        for (int i = 0; i < 3; ++i) {          // own units (hide shfl latency)
            const v2f f2 = (v2f){c[i], c[i]};
            nv01 = VFMA(wl01[i], f2, nv01);
            nv23 = VFMA(wl23[i], f2, nv23);
            nv4  = __builtin_fmaf(wl4[i], c[i], nv4);
        }
        #pragma unroll
        for (int i = 0; i < 3; ++i) {          // partner units
            const v2f f2 = (v2f){p[i], p[i]};
            nv01 = VFMA(wl01[3 + i], f2, nv01);
            nv23 = VFMA(wl23[3 + i], f2, nv23);
            nv4  = __builtin_fmaf(wl4[3 + i], p[i], nv4);
        }
    };

    v2f v01, v23; float v4;
    stageA(v01, v23, v4);                      // t = 0 partials

    const int q  = lane >> 4;                  // quadrant 0..3
    const int bo = (q & 1) * 2 + (q >> 1) * 5; // {0,2,5,7}
    const int to = 4 + (q >> 1) * 5;           // {4,4,9,9}
    const int row = wid * 4 + (lane & 3);      // 32 rows total

    #pragma unroll
    for (int t = 0; t < 16; ++t) {
        // level-2 reduce issue (xor16) — latency hidden by next stageA
        v2f s01, s23; float s4;
        s01.x = __shfl_xor(v01.x, 16);
        s01.y = __shfl_xor(v01.y, 16);
        s23.x = __shfl_xor(v23.x, 16);
        s23.y = __shfl_xor(v23.y, 16);
        s4    = __shfl_xor(v4, 16);

        v2f nv01, nv23; float nv4;
        if (t < 15) {
            stageA(nv01, nv23, nv4);
        } else {
            nv01 = (v2f){0.0f, 0.0f};
            nv23 = (v2f){0.0f, 0.0f};
            nv4  = 0.0f;
        }

        // fold 5 -> 3 and levels xor8, xor4
        const v2f a01 = v01 + s01;
        const v2f a23 = v23 + s23;
        const float a4 = v4 + s4;
        v2f w01;
        w01.x = hi16 ? a23.x : a01.x;
        w01.y = hi16 ? a23.y : a01.y;
        float w2 = a4;
        w01.x += __shfl_xor(w01.x, 8);
        w01.y += __shfl_xor(w01.y, 8);
        w2    += __shfl_xor(w2, 8);
        w01.x += __shfl_xor(w01.x, 4);
        w01.y += __shfl_xor(w01.y, 4);
        w2    += __shfl_xor(w2, 4);

        // 4 rows per wave; duplicate equal-value writes of w2 are benign
        if ((lane & 12) == 0) {
            const int base = row * 165 + t * 10;
            sred[base + bo]     = w01.x;
            sred[base + bo + 1] = w01.y;
            sred[base + to]     = w2;
        }

        v01 = nv01; v23 = nv23; v4 = nv4;
    }
    __syncthreads();

    // ---- final reduce: 160 threads, one (t,o) each, 32 rows ----
    if (tid < 160) {
        float sum = 0.0f;
        #pragma unroll
        for (int r = 0; r < 32; ++r)
            sum += sred[r * 165 + tid];
        scur2[tid] = sum;
    }
    __syncthreads();

    // ---- LIF-2 scan, 10 lanes ----
    if (tid < 10) {
        float m2 = 0.0f, cnt = 0.0f;
        #pragma unroll
        for (int t = 0; t < 16; ++t) {
            m2 = __builtin_fmaf(0.5f, m2, scur2[t * 10 + tid]);
            float ms = m2 - 1.0f;
            bool  sp = ms > 0.0f;
            m2  = sp ? ms : m2;
            cnt += sp ? 1.0f : 0.0f;
        }
        out[(size_t)b * 10 + tid] = cnt;
    }
}

extern "C" void kernel_launch(void* const* d_in, const int* in_sizes, int n_in,
                              void* d_out, int out_size, void* d_ws, size_t ws_size,
                              hipStream_t stream) {
    const float* x      = (const float*)d_in[0];  // 4096*784
    const float* conv_w = (const float*)d_in[1];  // 72
    const float* fc_w   = (const float*)d_in[2];  // 13520
    float* out          = (float*)d_out;          // 40960

    const int B = in_sizes[0] / 784;              // 4096
    snn_fused_kernel<<<B, 512, 0, stream>>>(x, conv_w, fc_w, out);
}